// Round 1
// baseline (367.295 us; speedup 1.0000x reference)
//
#include <hip/hip_runtime.h>

// ---------------------------------------------------------------------------
// MHSA fused block, MI355X (gfx950).
// Pipeline: fold(BN->W) -> pos table -> QKV projection GEMM (bf16 MFMA,
// split hi/lo for q,k) -> flash attention (swapped QK^T, online softmax,
// PV via MFMA, fused residual).
// Workspace requirement: ~35.2 MB.
// ---------------------------------------------------------------------------

typedef __attribute__((ext_vector_type(8))) short bf16x8;
typedef __attribute__((ext_vector_type(4))) float f32x4;

#define MFMA16(a, b, c) __builtin_amdgcn_mfma_f32_16x16x32_bf16(a, b, c, 0, 0, 0)

__device__ __forceinline__ unsigned short f2bf(float f) {
  union { float f; unsigned u; } v; v.f = f;
  unsigned r = v.u + 0x7fffu + ((v.u >> 16) & 1u);
  return (unsigned short)(r >> 16);
}
__device__ __forceinline__ float bf2f(unsigned short h) {
  union { unsigned u; float f; } v; v.u = ((unsigned)h) << 16;
  return v.f;
}

// ---------------------------------------------------------------------------
// Fold BN into conv weights. Wf[768][512] bf16 (rows: 128 q, 128 k, 512 v),
// Wflo[256][512] bf16 residual for q,k rows, bfv[768] f32 fused bias.
// ---------------------------------------------------------------------------
__global__ __launch_bounds__(256) void fold_kernel(
    const float* __restrict__ Wq, const float* __restrict__ bq,
    const float* __restrict__ qg, const float* __restrict__ qbe,
    const float* __restrict__ qme, const float* __restrict__ qva,
    const float* __restrict__ Wk, const float* __restrict__ bk,
    const float* __restrict__ kg, const float* __restrict__ kbe,
    const float* __restrict__ kme, const float* __restrict__ kva,
    const float* __restrict__ Wv, const float* __restrict__ bv,
    const float* __restrict__ vg, const float* __restrict__ vbe,
    const float* __restrict__ vme, const float* __restrict__ vva,
    unsigned short* __restrict__ Wf, unsigned short* __restrict__ Wflo,
    float* __restrict__ bfv)
{
  int idx = blockIdx.x * 256 + threadIdx.x;
  if (idx >= 768 * 512) return;
  int o = idx >> 9, c = idx & 511;
  float w, sc, bb, mean, beta;
  if (o < 128) {
    sc = qg[o] / sqrtf(qva[o] + 1e-5f);
    w = Wq[o * 512 + c]; bb = bq[o]; mean = qme[o]; beta = qbe[o];
  } else if (o < 256) {
    int r = o - 128;
    sc = kg[r] / sqrtf(kva[r] + 1e-5f);
    w = Wk[r * 512 + c]; bb = bk[r]; mean = kme[r]; beta = kbe[r];
  } else {
    int r = o - 256;
    sc = vg[r] / sqrtf(vva[r] + 1e-5f);
    w = Wv[r * 512 + c]; bb = bv[r]; mean = vme[r]; beta = vbe[r];
  }
  float wsc = w * sc;
  unsigned short hi = f2bf(wsc);
  Wf[idx] = hi;
  if (o < 256) Wflo[idx] = f2bf(wsc - bf2f(hi));
  if (c == 0) bfv[o] = (bb - mean) * sc + beta;
}

// ---------------------------------------------------------------------------
// pos[h][n][d] = rel_h[h,d,hh] + rel_w[h,d,w], n = w*32+hh. hi + lo bf16.
// ---------------------------------------------------------------------------
__global__ __launch_bounds__(256) void pos_kernel(
    const float* __restrict__ rel_h, const float* __restrict__ rel_w,
    unsigned short* __restrict__ posT, unsigned short* __restrict__ posTlo)
{
  int idx = blockIdx.x * 256 + threadIdx.x;  // [h][n][d] : 4*1024*32
  if (idx >= 4 * 1024 * 32) return;
  int h = idx >> 15, rem = idx & 32767, n = rem >> 5, d = rem & 31;
  int w = n >> 5, hh = n & 31;
  float v = rel_h[(h * 32 + d) * 32 + hh] + rel_w[(h * 32 + d) * 32 + w];
  unsigned short hi = f2bf(v);
  posT[idx] = hi;
  posTlo[idx] = f2bf(v - bf2f(hi));
}

// ---------------------------------------------------------------------------
// Projection GEMM: per batch b, Y[768][1024] = Wf[768][512] * x_b[512][1024].
// Tile 128x128, BK=64, 4 waves (2x2), 16x16x32 bf16 MFMA, f32 accumulate.
// q,k rows use 3-term hi/lo split (precision). Outputs:
//   qT/qloT [B*H][1024][32] (position-major), kT/kloT same, V [B*H][128][1024].
// ---------------------------------------------------------------------------
__global__ __launch_bounds__(256) void proj_kernel(
    const float* __restrict__ x,
    const unsigned short* __restrict__ Wf, const unsigned short* __restrict__ Wflo,
    const float* __restrict__ bfv,
    unsigned short* __restrict__ qT, unsigned short* __restrict__ qloT,
    unsigned short* __restrict__ kT, unsigned short* __restrict__ kloT,
    unsigned short* __restrict__ Vm)
{
  // 4 LDS tiles [128][72 shorts] (stride 144B, 16B aligned rows)
  __shared__ __align__(16) short sm[4 * 128 * 72];
  short* At  = sm;                 // Wf hi
  short* Atl = sm + 128 * 72;      // Wf lo
  short* Bt  = sm + 2 * 128 * 72;  // x hi (transposed, xor-swizzled chunks)
  short* Btl = sm + 3 * 128 * 72;  // x lo

  int bid = blockIdx.x;
  int b = bid / 48, rem = bid % 48, mblk = rem >> 3, nblk = rem & 7;
  int Mb = mblk * 128, Nb = nblk * 128;
  bool prec = (mblk < 2);  // q,k rows
  int t = threadIdx.x;
  int lane = t & 63, wvid = t >> 6, ln = lane & 15, g = lane >> 4;
  int wm = wvid >> 1, wn = wvid & 1;

  f32x4 acc[4][4];
  for (int i = 0; i < 4; i++)
    for (int j = 0; j < 4; j++) acc[i][j] = (f32x4){0.f, 0.f, 0.f, 0.f};

  for (int kb = 0; kb < 512; kb += 64) {
    __syncthreads();
    // stage A (Wf rows Mb..Mb+127, k kb..kb+63)
    for (int i = 0; i < 4; i++) {
      int o = i * 32 + (t >> 3), ch = t & 7;
      *(bf16x8*)&At[o * 72 + ch * 8] =
          *(const bf16x8*)&Wf[(Mb + o) * 512 + kb + ch * 8];
    }
    if (prec) {
      for (int i = 0; i < 4; i++) {
        int o = i * 32 + (t >> 3), ch = t & 7;
        *(bf16x8*)&Atl[o * 72 + ch * 8] =
            *(const bf16x8*)&Wflo[(Mb + o) * 512 + kb + ch * 8];
      }
    }
    // stage B: x[b][kb..kb+63][Nb..Nb+127] -> LDS [n][k] bf16 (transpose)
    for (int i = 0; i < 8; i++) {
      int f4 = i * 256 + t;
      int k = f4 >> 5, n4 = (f4 & 31) << 2;
      float4 v4 = *(const float4*)&x[(b * 512 + kb + k) * 1024 + Nb + n4];
      const float* vp = (const float*)&v4;
      for (int e = 0; e < 4; e++) {
        int n = n4 + e;
        int so = n * 72 + (k ^ ((n & 7) << 3));  // xor-swizzle 8-short chunks
        unsigned short hi = f2bf(vp[e]);
        Bt[so] = (short)hi;
        if (prec) Btl[so] = (short)f2bf(vp[e] - bf2f(hi));
      }
    }
    __syncthreads();

    bf16x8 afh[4][2], bfh[4][2], afl[4][2], bfl[4][2];
    for (int mt = 0; mt < 4; mt++)
      for (int ks = 0; ks < 2; ks++) {
        int o = wm * 64 + mt * 16 + ln;
        afh[mt][ks] = *(const bf16x8*)&At[o * 72 + ks * 32 + g * 8];
        if (prec) afl[mt][ks] = *(const bf16x8*)&Atl[o * 72 + ks * 32 + g * 8];
      }
    for (int nt = 0; nt < 4; nt++)
      for (int ks = 0; ks < 2; ks++) {
        int n = wn * 64 + nt * 16 + ln;
        int so = n * 72 + ((ks * 32 + g * 8) ^ ((n & 7) << 3));
        bfh[nt][ks] = *(const bf16x8*)&Bt[so];
        if (prec) bfl[nt][ks] = *(const bf16x8*)&Btl[so];
      }
    for (int ks = 0; ks < 2; ks++)
      for (int mt = 0; mt < 4; mt++)
        for (int nt = 0; nt < 4; nt++) {
          acc[mt][nt] = MFMA16(afh[mt][ks], bfh[nt][ks], acc[mt][nt]);
          if (prec) {
            acc[mt][nt] = MFMA16(afh[mt][ks], bfl[nt][ks], acc[mt][nt]);
            acc[mt][nt] = MFMA16(afl[mt][ks], bfh[nt][ks], acc[mt][nt]);
          }
        }
  }

  // epilogue: bias + route to qT/kT (transposed, hi+lo) or V (natural)
  for (int mt = 0; mt < 4; mt++)
    for (int nt = 0; nt < 4; nt++)
      for (int r = 0; r < 4; r++) {
        int o = Mb + wm * 64 + mt * 16 + g * 4 + r;
        int n = Nb + wn * 64 + nt * 16 + ln;
        float y = acc[mt][nt][r] + bfv[o];
        unsigned short hi = f2bf(y);
        if (o < 128) {
          int h = o >> 5, d = o & 31;
          int gi = ((b * 4 + h) * 1024 + n) * 32 + d;
          qT[gi] = hi;
          qloT[gi] = f2bf(y - bf2f(hi));
        } else if (o < 256) {
          int o2 = o - 128, h = o2 >> 5, d = o2 & 31;
          int gi = ((b * 4 + h) * 1024 + n) * 32 + d;
          kT[gi] = hi;
          kloT[gi] = f2bf(y - bf2f(hi));
        } else {
          int o2 = o - 256, h = o2 >> 7, cc = o2 & 127;
          Vm[((b * 4 + h) * 128 + cc) * 1024 + n] = hi;
        }
      }
}

// ---------------------------------------------------------------------------
// Flash attention. Block = (b,h, 128-query tile), 4 waves x 32 rows.
// S^T[j][i] = q_i.k_j + pos_i.q_j computed with swapped operands so the
// softmax stats land in the col=lane&15 layout the PV accumulator uses.
// Split hi/lo (3-term) products for the score path. Online softmax.
// PV: D[c][m] = sum_n V[c][n] P[m][n]; P goes through per-wave LDS.
// Epilogue: out = acc/l + x (residual).
// ---------------------------------------------------------------------------
__global__ __launch_bounds__(256) void attn_kernel(
    const float* __restrict__ x,
    const unsigned short* __restrict__ qT, const unsigned short* __restrict__ qloT,
    const unsigned short* __restrict__ kT, const unsigned short* __restrict__ kloT,
    const unsigned short* __restrict__ posT, const unsigned short* __restrict__ posTlo,
    const unsigned short* __restrict__ Vm,
    float* __restrict__ out)
{
  // LDS (short offsets):
  //   0      K_hi [64][40]      2560   K_lo
  //   5120   Qk_hi               7680   Qk_lo
  //   10240  V [128][64] xor-swizzled
  //   18432  P [4 waves][2 qsub][16][72]
  __shared__ __align__(16) short sm[18432 + 4 * 2 * 16 * 72];

  int bid = blockIdx.x;
  int bh = bid >> 3, qt = bid & 7;
  int b = bh >> 2, h = bh & 3;
  int t = threadIdx.x;
  int lane = t & 63, wvid = t >> 6, ln = lane & 15, g = lane >> 4;

  // own-query B-fragments (col = ln), loaded once from global
  bf16x8 bQh[2], bQl[2], bPh[2], bPl[2];
  for (int qs = 0; qs < 2; qs++) {
    int qrow = qt * 128 + wvid * 32 + qs * 16 + ln;
    int gi = (bh * 1024 + qrow) * 32 + g * 8;
    bQh[qs] = *(const bf16x8*)&qT[gi];
    bQl[qs] = *(const bf16x8*)&qloT[gi];
    int pi = (h * 1024 + qrow) * 32 + g * 8;
    bPh[qs] = *(const bf16x8*)&posT[pi];
    bPl[qs] = *(const bf16x8*)&posTlo[pi];
  }

  f32x4 acc[2][8];
  for (int qs = 0; qs < 2; qs++)
    for (int ct = 0; ct < 8; ct++) acc[qs][ct] = (f32x4){0.f, 0.f, 0.f, 0.f};
  float m_run[2] = {-1e30f, -1e30f};
  float l_run[2] = {0.f, 0.f};

  short* Pbuf = &sm[18432 + wvid * (2 * 16 * 72)];

  for (int jb = 0; jb < 1024; jb += 64) {
    __syncthreads();
    {  // stage K/Q key tiles: 64 rows x 32 d, stride 40 shorts
      int j = t >> 2, ch = t & 3;
      int gi = (bh * 1024 + jb + j) * 32 + ch * 8;
      int so = j * 40 + ch * 8;
      *(bf16x8*)&sm[so]        = *(const bf16x8*)&kT[gi];
      *(bf16x8*)&sm[2560 + so] = *(const bf16x8*)&kloT[gi];
      *(bf16x8*)&sm[5120 + so] = *(const bf16x8*)&qT[gi];
      *(bf16x8*)&sm[7680 + so] = *(const bf16x8*)&qloT[gi];
    }
    for (int i = 0; i < 4; i++) {  // stage V tile [128][64], xor-swizzled
      int c = i * 32 + (t >> 3), gg = t & 7;
      *(bf16x8*)&sm[10240 + c * 64 + ((gg * 8) ^ ((c & 7) << 3))] =
          *(const bf16x8*)&Vm[(bh * 128 + c) * 1024 + jb + gg * 8];
    }
    __syncthreads();

    bf16x8 aKh[4], aKl[4], aQh[4], aQl[4];
    for (int kt = 0; kt < 4; kt++) {
      int so = (kt * 16 + ln) * 40 + g * 8;
      aKh[kt] = *(const bf16x8*)&sm[so];
      aKl[kt] = *(const bf16x8*)&sm[2560 + so];
      aQh[kt] = *(const bf16x8*)&sm[5120 + so];
      aQl[kt] = *(const bf16x8*)&sm[7680 + so];
    }

    for (int qs = 0; qs < 2; qs++) {
      f32x4 s[4];
      for (int kt = 0; kt < 4; kt++) s[kt] = (f32x4){0.f, 0.f, 0.f, 0.f};
      // S^T = k.q (cc) + q.pos (cp), hi/lo 3-term each
      for (int kt = 0; kt < 4; kt++) s[kt] = MFMA16(aKh[kt], bQh[qs], s[kt]);
      for (int kt = 0; kt < 4; kt++) s[kt] = MFMA16(aKh[kt], bQl[qs], s[kt]);
      for (int kt = 0; kt < 4; kt++) s[kt] = MFMA16(aKl[kt], bQh[qs], s[kt]);
      for (int kt = 0; kt < 4; kt++) s[kt] = MFMA16(aQh[kt], bPh[qs], s[kt]);
      for (int kt = 0; kt < 4; kt++) s[kt] = MFMA16(aQh[kt], bPl[qs], s[kt]);
      for (int kt = 0; kt < 4; kt++) s[kt] = MFMA16(aQl[kt], bPh[qs], s[kt]);

      // online softmax for query i = ln (keys spread over regs + g groups)
      float mx = -1e30f;
      for (int kt = 0; kt < 4; kt++)
        for (int r = 0; r < 4; r++) mx = fmaxf(mx, s[kt][r]);
      mx = fmaxf(mx, __shfl_xor(mx, 16));
      mx = fmaxf(mx, __shfl_xor(mx, 32));
      float mnew = fmaxf(m_run[qs], mx);
      float scl = __expf(m_run[qs] - mnew);
      float rs = 0.f;
      for (int kt = 0; kt < 4; kt++)
        for (int r = 0; r < 4; r++) {
          float p = __expf(s[kt][r] - mnew);
          s[kt][r] = p;
          rs += p;
        }
      rs += __shfl_xor(rs, 16);
      rs += __shfl_xor(rs, 32);
      l_run[qs] = l_run[qs] * scl + rs;
      m_run[qs] = mnew;
      for (int ct = 0; ct < 8; ct++) acc[qs][ct] *= scl;

      // P^T -> LDS [i=ln][j], packed pairs (r is contiguous in j)
      for (int kt = 0; kt < 4; kt++)
        for (int pr = 0; pr < 2; pr++) {
          unsigned pk = (unsigned)f2bf(s[kt][2 * pr]) |
                        ((unsigned)f2bf(s[kt][2 * pr + 1]) << 16);
          *(unsigned*)&Pbuf[qs * 1152 + ln * 72 + kt * 16 + g * 4 + pr * 2] = pk;
        }
    }
    asm volatile("s_waitcnt lgkmcnt(0)" ::: "memory");
    __builtin_amdgcn_sched_barrier(0);

    bf16x8 bP[2][2];
    for (int qs = 0; qs < 2; qs++)
      for (int st2 = 0; st2 < 2; st2++)
        bP[qs][st2] = *(const bf16x8*)&Pbuf[qs * 1152 + ln * 72 + st2 * 32 + g * 8];

    for (int ct = 0; ct < 8; ct++)
      for (int st2 = 0; st2 < 2; st2++) {
        int c = ct * 16 + ln;
        bf16x8 av = *(const bf16x8*)&sm[10240 + c * 64 +
                                        ((st2 * 32 + g * 8) ^ ((c & 7) << 3))];
        acc[0][ct] = MFMA16(av, bP[0][st2], acc[0][ct]);
        acc[1][ct] = MFMA16(av, bP[1][st2], acc[1][ct]);
      }
  }

  // epilogue: normalize, add residual, coalesced store (col = m = ln)
  for (int qs = 0; qs < 2; qs++) {
    float inv = 1.0f / l_run[qs];
    int m = qt * 128 + wvid * 32 + qs * 16 + ln;
    for (int ct = 0; ct < 8; ct++)
      for (int r = 0; r < 4; r++) {
        int c = h * 128 + ct * 16 + g * 4 + r;
        int gi = (b * 512 + c) * 1024 + m;
        out[gi] = acc[qs][ct][r] * inv + x[gi];
      }
  }
}

// ---------------------------------------------------------------------------
extern "C" void kernel_launch(void* const* d_in, const int* in_sizes, int n_in,
                              void* d_out, int out_size, void* d_ws, size_t ws_size,
                              hipStream_t stream) {
  const float* x    = (const float*)d_in[0];
  const float* Wq   = (const float*)d_in[1];
  const float* bq   = (const float*)d_in[2];
  const float* qg   = (const float*)d_in[3];
  const float* qbe  = (const float*)d_in[4];
  const float* qme  = (const float*)d_in[5];
  const float* qva  = (const float*)d_in[6];
  const float* Wk   = (const float*)d_in[7];
  const float* bk   = (const float*)d_in[8];
  const float* kg   = (const float*)d_in[9];
  const float* kbe  = (const float*)d_in[10];
  const float* kme  = (const float*)d_in[11];
  const float* kva  = (const float*)d_in[12];
  const float* Wv   = (const float*)d_in[13];
  const float* bv   = (const float*)d_in[14];
  const float* vg   = (const float*)d_in[15];
  const float* vbe  = (const float*)d_in[16];
  const float* vme  = (const float*)d_in[17];
  const float* vva  = (const float*)d_in[18];
  const float* relh = (const float*)d_in[19];
  const float* relw = (const float*)d_in[20];
  float* outp = (float*)d_out;

  unsigned char* ws = (unsigned char*)d_ws;
  unsigned short* Wf     = (unsigned short*)(ws + 0);         //  768*512*2
  unsigned short* Wflo   = (unsigned short*)(ws + 786432);    //  256*512*2
  float*          bfv    = (float*)(ws + 1048576);            //  768*4
  unsigned short* qTp    = (unsigned short*)(ws + 1051648);   //  64*1024*32*2
  unsigned short* qloTp  = (unsigned short*)(ws + 5245952);
  unsigned short* kTp    = (unsigned short*)(ws + 9440256);
  unsigned short* kloTp  = (unsigned short*)(ws + 13634560);
  unsigned short* posTp  = (unsigned short*)(ws + 17828864);  //  4*1024*32*2
  unsigned short* posTlp = (unsigned short*)(ws + 18091008);
  unsigned short* Vmp    = (unsigned short*)(ws + 18353152);  //  64*128*1024*2
  // total ws used: 35,130,368 bytes

  fold_kernel<<<1536, 256, 0, stream>>>(Wq, bq, qg, qbe, qme, qva,
                                        Wk, bk, kg, kbe, kme, kva,
                                        Wv, bv, vg, vbe, vme, vva,
                                        Wf, Wflo, bfv);
  pos_kernel<<<512, 256, 0, stream>>>(relh, relw, posTp, posTlp);
  proj_kernel<<<768, 256, 0, stream>>>(x, Wf, Wflo, bfv,
                                       qTp, qloTp, kTp, kloTp, Vmp);
  attn_kernel<<<512, 256, 0, stream>>>(x, qTp, qloTp, kTp, kloTp,
                                       posTp, posTlp, Vmp, outp);
}

// Round 2
// 161.340 us; speedup vs baseline: 2.2765x; 2.2765x over previous
//
#include <hip/hip_runtime.h>

// ---------------------------------------------------------------------------
// MHSA fused block, MI355X (gfx950).
// fold(BN->W) -> pos table -> QKV projection GEMM (bf16 MFMA, hi/lo split
// for q,k, LDS-transposed coalesced epilogue) -> flash attention.
// ---------------------------------------------------------------------------

typedef __attribute__((ext_vector_type(8))) short bf16x8;
typedef __attribute__((ext_vector_type(4))) float f32x4;
typedef __attribute__((ext_vector_type(4))) unsigned int u32x4;

#define MFMA16(a, b, c) __builtin_amdgcn_mfma_f32_16x16x32_bf16(a, b, c, 0, 0, 0)

__device__ __forceinline__ unsigned short f2bf(float f) {
  union { float f; unsigned u; } v; v.f = f;
  unsigned r = v.u + 0x7fffu + ((v.u >> 16) & 1u);
  return (unsigned short)(r >> 16);
}
__device__ __forceinline__ float bf2f(unsigned short h) {
  union { unsigned u; float f; } v; v.u = ((unsigned)h) << 16;
  return v.f;
}

// ---------------------------------------------------------------------------
// Fold BN into conv weights. Wf[768][512] bf16 (rows: 128 q, 128 k, 512 v),
// Wflo[256][512] bf16 residual for q,k rows, bfv[768] f32 fused bias.
// ---------------------------------------------------------------------------
__global__ __launch_bounds__(256) void fold_kernel(
    const float* __restrict__ Wq, const float* __restrict__ bq,
    const float* __restrict__ qg, const float* __restrict__ qbe,
    const float* __restrict__ qme, const float* __restrict__ qva,
    const float* __restrict__ Wk, const float* __restrict__ bk,
    const float* __restrict__ kg, const float* __restrict__ kbe,
    const float* __restrict__ kme, const float* __restrict__ kva,
    const float* __restrict__ Wv, const float* __restrict__ bv,
    const float* __restrict__ vg, const float* __restrict__ vbe,
    const float* __restrict__ vme, const float* __restrict__ vva,
    unsigned short* __restrict__ Wf, unsigned short* __restrict__ Wflo,
    float* __restrict__ bfv)
{
  int idx = blockIdx.x * 256 + threadIdx.x;
  if (idx >= 768 * 512) return;
  int o = idx >> 9, c = idx & 511;
  float w, sc, bb, mean, beta;
  if (o < 128) {
    sc = qg[o] / sqrtf(qva[o] + 1e-5f);
    w = Wq[o * 512 + c]; bb = bq[o]; mean = qme[o]; beta = qbe[o];
  } else if (o < 256) {
    int r = o - 128;
    sc = kg[r] / sqrtf(kva[r] + 1e-5f);
    w = Wk[r * 512 + c]; bb = bk[r]; mean = kme[r]; beta = kbe[r];
  } else {
    int r = o - 256;
    sc = vg[r] / sqrtf(vva[r] + 1e-5f);
    w = Wv[r * 512 + c]; bb = bv[r]; mean = vme[r]; beta = vbe[r];
  }
  float wsc = w * sc;
  // truncation split: hi = top16(w), lo = top16(w - hi); sum is exact split
  unsigned uw = __float_as_uint(wsc);
  unsigned short hi = (unsigned short)(uw >> 16);
  Wf[idx] = hi;
  if (o < 256) {
    float lof = wsc - __uint_as_float(uw & 0xffff0000u);
    Wflo[idx] = (unsigned short)(__float_as_uint(lof) >> 16);
  }
  if (c == 0) bfv[o] = (bb - mean) * sc + beta;
}

// ---------------------------------------------------------------------------
// pos[h][n][d] = rel_h[h,d,hh] + rel_w[h,d,w], n = w*32+hh. hi + lo bf16.
// ---------------------------------------------------------------------------
__global__ __launch_bounds__(256) void pos_kernel(
    const float* __restrict__ rel_h, const float* __restrict__ rel_w,
    unsigned short* __restrict__ posT, unsigned short* __restrict__ posTlo)
{
  int idx = blockIdx.x * 256 + threadIdx.x;  // [h][n][d] : 4*1024*32
  if (idx >= 4 * 1024 * 32) return;
  int h = idx >> 15, rem = idx & 32767, n = rem >> 5, d = rem & 31;
  int w = n >> 5, hh = n & 31;
  float v = rel_h[(h * 32 + d) * 32 + hh] + rel_w[(h * 32 + d) * 32 + w];
  unsigned uv = __float_as_uint(v);
  posT[idx] = (unsigned short)(uv >> 16);
  float lof = v - __uint_as_float(uv & 0xffff0000u);
  posTlo[idx] = (unsigned short)(__float_as_uint(lof) >> 16);
}

// ---------------------------------------------------------------------------
// Projection GEMM: per batch b, Y[768][1024] = Wf[768][512] * x_b[512][1024].
// Tile 128x128, BK=64, 4 waves (2x2). LDS 48KB -> 3 blocks/CU (768 grid fit).
// A-hi tile [128][64] chunk-XOR-swizzled; A-lo read direct from L2.
// B staged via float2 micro-tiles -> b128 swizzled LDS writes.
// Epilogue: LDS transpose -> fully coalesced 16B stores.
// ---------------------------------------------------------------------------
__global__ __launch_bounds__(256) void proj_kernel(
    const float* __restrict__ x,
    const unsigned short* __restrict__ Wf, const unsigned short* __restrict__ Wflo,
    const float* __restrict__ bfv,
    unsigned short* __restrict__ qT, unsigned short* __restrict__ qloT,
    unsigned short* __restrict__ kT, unsigned short* __restrict__ kloT,
    unsigned short* __restrict__ Vm)
{
  __shared__ __align__(16) short sm[24576];  // 49152 B
  short* At  = sm;           // [128 rows][8 chunks of 8] swizzled, 16 KB
  short* Bt  = sm + 8192;    // [128 n][8 chunks] swizzled hi, 16 KB
  short* Btl = sm + 16384;   // lo, 16 KB

  int bid = blockIdx.x;
  int b = bid / 48, rem = bid % 48, mblk = rem >> 3, nblk = rem & 7;
  int Mb = mblk * 128, Nb = nblk * 128;
  bool prec = (mblk < 2);
  int t = threadIdx.x;
  int lane = t & 63, wvid = t >> 6, ln = lane & 15, g = lane >> 4;
  int wm = wvid >> 1, wn = wvid & 1;
  int kgp = t >> 5, lp = t & 31;

  f32x4 acc[4][4];
  for (int i = 0; i < 4; i++)
    for (int j = 0; j < 4; j++) acc[i][j] = (f32x4){0.f, 0.f, 0.f, 0.f};

  for (int kb = 0; kb < 512; kb += 64) {
    __syncthreads();
    // ---- stage A-hi: chunk j stored at position j ^ (row&7)
    for (int ii = 0; ii < 4; ii++) {
      int idx = ii * 256 + t;
      int row = idx >> 3, pos = idx & 7;
      int j = pos ^ (row & 7);
      *(bf16x8*)&At[row * 64 + pos * 8] =
          *(const bf16x8*)&Wf[(Mb + row) * 512 + kb + j * 8];
    }
    // ---- stage B: thread covers k rows kgp*8..+7, n pairs {2lp,2lp+1}+64e
    for (int e = 0; e < 2; e++) {
      float2 f[8];
      for (int rr = 0; rr < 8; rr++)
        f[rr] = *(const float2*)&x[(b * 512 + kb + kgp * 8 + rr) * 1024 +
                                   Nb + 2 * lp + 64 * e];
      int n0 = 2 * lp + 64 * e, n1 = n0 + 1;
      unsigned h0[4], h1[4], l0[4], l1[4];
      for (int pr = 0; pr < 4; pr++) {
        unsigned ua = __float_as_uint(f[2 * pr].x);
        unsigned ub = __float_as_uint(f[2 * pr + 1].x);
        unsigned va = __float_as_uint(f[2 * pr].y);
        unsigned vb = __float_as_uint(f[2 * pr + 1].y);
        h0[pr] = (ua >> 16) | (ub & 0xffff0000u);
        h1[pr] = (va >> 16) | (vb & 0xffff0000u);
        if (prec) {
          float lax = f[2 * pr].x - __uint_as_float(ua & 0xffff0000u);
          float lbx = f[2 * pr + 1].x - __uint_as_float(ub & 0xffff0000u);
          float lay = f[2 * pr].y - __uint_as_float(va & 0xffff0000u);
          float lby = f[2 * pr + 1].y - __uint_as_float(vb & 0xffff0000u);
          l0[pr] = (__float_as_uint(lax) >> 16) | (__float_as_uint(lbx) & 0xffff0000u);
          l1[pr] = (__float_as_uint(lay) >> 16) | (__float_as_uint(lby) & 0xffff0000u);
        }
      }
      *(u32x4*)&Bt[n0 * 64 + 8 * (kgp ^ (n0 & 7))] = (u32x4){h0[0], h0[1], h0[2], h0[3]};
      *(u32x4*)&Bt[n1 * 64 + 8 * (kgp ^ (n1 & 7))] = (u32x4){h1[0], h1[1], h1[2], h1[3]};
      if (prec) {
        *(u32x4*)&Btl[n0 * 64 + 8 * (kgp ^ (n0 & 7))] = (u32x4){l0[0], l0[1], l0[2], l0[3]};
        *(u32x4*)&Btl[n1 * 64 + 8 * (kgp ^ (n1 & 7))] = (u32x4){l1[0], l1[1], l1[2], l1[3]};
      }
    }
    __syncthreads();

    // ---- fragments
    bf16x8 afh[4][2], afl[4][2], bfh[4][2], bfl[4][2];
    for (int mt = 0; mt < 4; mt++)
      for (int ks = 0; ks < 2; ks++) {
        int o = wm * 64 + mt * 16 + ln;
        afh[mt][ks] = *(const bf16x8*)&At[o * 64 + 8 * ((ks * 4 + g) ^ (o & 7))];
        if (prec)
          afl[mt][ks] = *(const bf16x8*)&Wflo[(Mb + o) * 512 + kb + ks * 32 + g * 8];
      }
    for (int nt = 0; nt < 4; nt++)
      for (int ks = 0; ks < 2; ks++) {
        int n = wn * 64 + nt * 16 + ln;
        int so = n * 64 + 8 * ((ks * 4 + g) ^ (n & 7));
        bfh[nt][ks] = *(const bf16x8*)&Bt[so];
        if (prec) bfl[nt][ks] = *(const bf16x8*)&Btl[so];
      }
    for (int ks = 0; ks < 2; ks++)
      for (int mt = 0; mt < 4; mt++)
        for (int nt = 0; nt < 4; nt++) {
          acc[mt][nt] = MFMA16(afh[mt][ks], bfh[nt][ks], acc[mt][nt]);
          if (prec) {
            acc[mt][nt] = MFMA16(afh[mt][ks], bfl[nt][ks], acc[mt][nt]);
            acc[mt][nt] = MFMA16(afl[mt][ks], bfh[nt][ks], acc[mt][nt]);
          }
        }
  }

  // ---- epilogue: two n-half passes (pass p handles waves with wn==p)
  unsigned* smU = (unsigned*)sm;
  for (int p = 0; p < 2; p++) {
    __syncthreads();
    if (wn == p) {
      if (mblk < 2) {
        // q/k: LDS [nl][o] u32 = hi | lo<<16, stride 132 dwords, b128 writes
        for (int mt = 0; mt < 4; mt++)
          for (int nt = 0; nt < 4; nt++) {
            u32x4 pk;
            for (int r = 0; r < 4; r++) {
              int o = wm * 64 + mt * 16 + g * 4 + r;
              float y = acc[mt][nt][r] + bfv[Mb + o];
              unsigned uy = __float_as_uint(y);
              float lof = y - __uint_as_float(uy & 0xffff0000u);
              pk[r] = (uy >> 16) | (__float_as_uint(lof) & 0xffff0000u);
            }
            int nl = nt * 16 + ln;
            *(u32x4*)&smU[nl * 132 + wm * 64 + mt * 16 + g * 4] = pk;
          }
      } else {
        // v: LDS [o][nl] u16, stride 72 shorts
        for (int mt = 0; mt < 4; mt++)
          for (int nt = 0; nt < 4; nt++)
            for (int r = 0; r < 4; r++) {
              int o = wm * 64 + mt * 16 + g * 4 + r;
              float y = acc[mt][nt][r] + bfv[Mb + o];
              sm[o * 72 + nt * 16 + ln] = (short)f2bf(y);
            }
      }
    }
    __syncthreads();
    if (mblk < 2) {
      unsigned short* dh = (mblk == 0) ? qT : kT;
      unsigned short* dl = (mblk == 0) ? qloT : kloT;
      for (int it = 0; it < 4; it++) {
        int task = it * 256 + t;
        int h = task >> 8, nl = (task >> 2) & 63, qc = task & 3;
        const unsigned* src = &smU[nl * 132 + h * 32 + qc * 8];
        u32x4 ua = *(const u32x4*)src;
        u32x4 ub = *(const u32x4*)(src + 4);
        u32x4 hi, lo;
        hi[0] = (ua[0] & 0xffffu) | (ua[1] << 16);
        hi[1] = (ua[2] & 0xffffu) | (ua[3] << 16);
        hi[2] = (ub[0] & 0xffffu) | (ub[1] << 16);
        hi[3] = (ub[2] & 0xffffu) | (ub[3] << 16);
        lo[0] = (ua[0] >> 16) | (ua[1] & 0xffff0000u);
        lo[1] = (ua[2] >> 16) | (ua[3] & 0xffff0000u);
        lo[2] = (ub[0] >> 16) | (ub[1] & 0xffff0000u);
        lo[3] = (ub[2] >> 16) | (ub[3] & 0xffff0000u);
        int gi = ((b * 4 + h) * 1024 + Nb + p * 64 + nl) * 32 + qc * 8;
        *(u32x4*)&dh[gi] = hi;
        *(u32x4*)&dl[gi] = lo;
      }
    } else {
      int bh = b * 4 + (mblk - 2);
      for (int it = 0; it < 4; it++) {
        int task = it * 256 + t;
        int o = task >> 3, qc = task & 7;
        u32x4 vv = *(const u32x4*)&sm[o * 72 + qc * 8];
        *(u32x4*)&Vm[(bh * 128 + o) * 1024 + Nb + p * 64 + qc * 8] = vv;
      }
    }
  }
}

// ---------------------------------------------------------------------------
// Flash attention (unchanged from round 1 — validated).
// ---------------------------------------------------------------------------
__global__ __launch_bounds__(256) void attn_kernel(
    const float* __restrict__ x,
    const unsigned short* __restrict__ qT, const unsigned short* __restrict__ qloT,
    const unsigned short* __restrict__ kT, const unsigned short* __restrict__ kloT,
    const unsigned short* __restrict__ posT, const unsigned short* __restrict__ posTlo,
    const unsigned short* __restrict__ Vm,
    float* __restrict__ out)
{
  __shared__ __align__(16) short sm[18432 + 4 * 2 * 16 * 72];

  int bid = blockIdx.x;
  int bh = bid >> 3, qt = bid & 7;
  int b = bh >> 2, h = bh & 3;
  int t = threadIdx.x;
  int lane = t & 63, wvid = t >> 6, ln = lane & 15, g = lane >> 4;

  bf16x8 bQh[2], bQl[2], bPh[2], bPl[2];
  for (int qs = 0; qs < 2; qs++) {
    int qrow = qt * 128 + wvid * 32 + qs * 16 + ln;
    int gi = (bh * 1024 + qrow) * 32 + g * 8;
    bQh[qs] = *(const bf16x8*)&qT[gi];
    bQl[qs] = *(const bf16x8*)&qloT[gi];
    int pi = (h * 1024 + qrow) * 32 + g * 8;
    bPh[qs] = *(const bf16x8*)&posT[pi];
    bPl[qs] = *(const bf16x8*)&posTlo[pi];
  }

  f32x4 acc[2][8];
  for (int qs = 0; qs < 2; qs++)
    for (int ct = 0; ct < 8; ct++) acc[qs][ct] = (f32x4){0.f, 0.f, 0.f, 0.f};
  float m_run[2] = {-1e30f, -1e30f};
  float l_run[2] = {0.f, 0.f};

  short* Pbuf = &sm[18432 + wvid * (2 * 16 * 72)];

  for (int jb = 0; jb < 1024; jb += 64) {
    __syncthreads();
    {
      int j = t >> 2, ch = t & 3;
      int gi = (bh * 1024 + jb + j) * 32 + ch * 8;
      int so = j * 40 + ch * 8;
      *(bf16x8*)&sm[so]        = *(const bf16x8*)&kT[gi];
      *(bf16x8*)&sm[2560 + so] = *(const bf16x8*)&kloT[gi];
      *(bf16x8*)&sm[5120 + so] = *(const bf16x8*)&qT[gi];
      *(bf16x8*)&sm[7680 + so] = *(const bf16x8*)&qloT[gi];
    }
    for (int i = 0; i < 4; i++) {
      int c = i * 32 + (t >> 3), gg = t & 7;
      *(bf16x8*)&sm[10240 + c * 64 + ((gg * 8) ^ ((c & 7) << 3))] =
          *(const bf16x8*)&Vm[(bh * 128 + c) * 1024 + jb + gg * 8];
    }
    __syncthreads();

    bf16x8 aKh[4], aKl[4], aQh[4], aQl[4];
    for (int kt = 0; kt < 4; kt++) {
      int so = (kt * 16 + ln) * 40 + g * 8;
      aKh[kt] = *(const bf16x8*)&sm[so];
      aKl[kt] = *(const bf16x8*)&sm[2560 + so];
      aQh[kt] = *(const bf16x8*)&sm[5120 + so];
      aQl[kt] = *(const bf16x8*)&sm[7680 + so];
    }

    for (int qs = 0; qs < 2; qs++) {
      f32x4 s[4];
      for (int kt = 0; kt < 4; kt++) s[kt] = (f32x4){0.f, 0.f, 0.f, 0.f};
      for (int kt = 0; kt < 4; kt++) s[kt] = MFMA16(aKh[kt], bQh[qs], s[kt]);
      for (int kt = 0; kt < 4; kt++) s[kt] = MFMA16(aKh[kt], bQl[qs], s[kt]);
      for (int kt = 0; kt < 4; kt++) s[kt] = MFMA16(aKl[kt], bQh[qs], s[kt]);
      for (int kt = 0; kt < 4; kt++) s[kt] = MFMA16(aQh[kt], bPh[qs], s[kt]);
      for (int kt = 0; kt < 4; kt++) s[kt] = MFMA16(aQh[kt], bPl[qs], s[kt]);
      for (int kt = 0; kt < 4; kt++) s[kt] = MFMA16(aQl[kt], bPh[qs], s[kt]);

      float mx = -1e30f;
      for (int kt = 0; kt < 4; kt++)
        for (int r = 0; r < 4; r++) mx = fmaxf(mx, s[kt][r]);
      mx = fmaxf(mx, __shfl_xor(mx, 16));
      mx = fmaxf(mx, __shfl_xor(mx, 32));
      float mnew = fmaxf(m_run[qs], mx);
      float scl = __expf(m_run[qs] - mnew);
      float rs = 0.f;
      for (int kt = 0; kt < 4; kt++)
        for (int r = 0; r < 4; r++) {
          float pv = __expf(s[kt][r] - mnew);
          s[kt][r] = pv;
          rs += pv;
        }
      rs += __shfl_xor(rs, 16);
      rs += __shfl_xor(rs, 32);
      l_run[qs] = l_run[qs] * scl + rs;
      m_run[qs] = mnew;
      for (int ct = 0; ct < 8; ct++) acc[qs][ct] *= scl;

      for (int kt = 0; kt < 4; kt++)
        for (int pr = 0; pr < 2; pr++) {
          unsigned pk = (unsigned)f2bf(s[kt][2 * pr]) |
                        ((unsigned)f2bf(s[kt][2 * pr + 1]) << 16);
          *(unsigned*)&Pbuf[qs * 1152 + ln * 72 + kt * 16 + g * 4 + pr * 2] = pk;
        }
    }
    asm volatile("s_waitcnt lgkmcnt(0)" ::: "memory");
    __builtin_amdgcn_sched_barrier(0);

    bf16x8 bP[2][2];
    for (int qs = 0; qs < 2; qs++)
      for (int st2 = 0; st2 < 2; st2++)
        bP[qs][st2] = *(const bf16x8*)&Pbuf[qs * 1152 + ln * 72 + st2 * 32 + g * 8];

    for (int ct = 0; ct < 8; ct++)
      for (int st2 = 0; st2 < 2; st2++) {
        int c = ct * 16 + ln;
        bf16x8 av = *(const bf16x8*)&sm[10240 + c * 64 +
                                        ((st2 * 32 + g * 8) ^ ((c & 7) << 3))];
        acc[0][ct] = MFMA16(av, bP[0][st2], acc[0][ct]);
        acc[1][ct] = MFMA16(av, bP[1][st2], acc[1][ct]);
      }
  }

  for (int qs = 0; qs < 2; qs++) {
    float inv = 1.0f / l_run[qs];
    int m = qt * 128 + wvid * 32 + qs * 16 + ln;
    for (int ct = 0; ct < 8; ct++)
      for (int r = 0; r < 4; r++) {
        int c = h * 128 + ct * 16 + g * 4 + r;
        int gi = (b * 512 + c) * 1024 + m;
        out[gi] = acc[qs][ct][r] * inv + x[gi];
      }
  }
}

// ---------------------------------------------------------------------------
extern "C" void kernel_launch(void* const* d_in, const int* in_sizes, int n_in,
                              void* d_out, int out_size, void* d_ws, size_t ws_size,
                              hipStream_t stream) {
  const float* x    = (const float*)d_in[0];
  const float* Wq   = (const float*)d_in[1];
  const float* bq   = (const float*)d_in[2];
  const float* qg   = (const float*)d_in[3];
  const float* qbe  = (const float*)d_in[4];
  const float* qme  = (const float*)d_in[5];
  const float* qva  = (const float*)d_in[6];
  const float* Wk   = (const float*)d_in[7];
  const float* bk   = (const float*)d_in[8];
  const float* kg   = (const float*)d_in[9];
  const float* kbe  = (const float*)d_in[10];
  const float* kme  = (const float*)d_in[11];
  const float* kva  = (const float*)d_in[12];
  const float* Wv   = (const float*)d_in[13];
  const float* bv   = (const float*)d_in[14];
  const float* vg   = (const float*)d_in[15];
  const float* vbe  = (const float*)d_in[16];
  const float* vme  = (const float*)d_in[17];
  const float* vva  = (const float*)d_in[18];
  const float* relh = (const float*)d_in[19];
  const float* relw = (const float*)d_in[20];
  float* outp = (float*)d_out;

  unsigned char* ws = (unsigned char*)d_ws;
  unsigned short* Wf     = (unsigned short*)(ws + 0);         //  768*512*2
  unsigned short* Wflo   = (unsigned short*)(ws + 786432);    //  256*512*2
  float*          bfv    = (float*)(ws + 1048576);            //  768*4
  unsigned short* qTp    = (unsigned short*)(ws + 1051648);   //  64*1024*32*2
  unsigned short* qloTp  = (unsigned short*)(ws + 5245952);
  unsigned short* kTp    = (unsigned short*)(ws + 9440256);
  unsigned short* kloTp  = (unsigned short*)(ws + 13634560);
  unsigned short* posTp  = (unsigned short*)(ws + 17828864);  //  4*1024*32*2
  unsigned short* posTlp = (unsigned short*)(ws + 18091008);
  unsigned short* Vmp    = (unsigned short*)(ws + 18353152);  //  64*128*1024*2
  // total ws used: 35,130,368 bytes

  fold_kernel<<<1536, 256, 0, stream>>>(Wq, bq, qg, qbe, qme, qva,
                                        Wk, bk, kg, kbe, kme, kva,
                                        Wv, bv, vg, vbe, vme, vva,
                                        Wf, Wflo, bfv);
  pos_kernel<<<512, 256, 0, stream>>>(relh, relw, posTp, posTlp);
  proj_kernel<<<768, 256, 0, stream>>>(x, Wf, Wflo, bfv,
                                       qTp, qloTp, kTp, kloTp, Vmp);
  attn_kernel<<<512, 256, 0, stream>>>(x, qTp, qloTp, kTp, kloTp,
                                       posTp, posTlp, Vmp, outp);
}